// Round 2
// baseline (1216.215 us; speedup 1.0000x reference)
//
#include <hip/hip_runtime.h>

#define DF 64
#define MSG 20
#define HID2 10
#define NODES 50000
#define EDGES 800000
#define GRAPHS 512
#define EPT 4
#define NTHREADS (EDGES / EPT)   // 200000

__global__ void zero_kernel(float* __restrict__ p, int n) {
    int i = blockIdx.x * blockDim.x + threadIdx.x;
    int stride = gridDim.x * blockDim.x;
    for (; i < n; i += stride) p[i] = 0.0f;
}

// 4 edges per thread. W staged in LDS (broadcast reads). 192->20 MLP, relu,
// atomic scatter-add into x1[dst].
__global__ __launch_bounds__(256) void edge_kernel(
    const int* __restrict__ ei,          // (2, E)
    const float* __restrict__ node_attr, // (N, 64)
    const float* __restrict__ edge_attr, // (E, 64)
    const float* __restrict__ W,         // (192, 20)
    const float* __restrict__ b,         // (20,)
    float* __restrict__ x1)              // (N, 20) accumulator
{
    __shared__ float Ws[3 * DF * MSG];   // 3840 floats = 15360 B
    __shared__ float bs[MSG];
    for (int i = threadIdx.x; i < 3 * DF * MSG; i += 256) Ws[i] = W[i];
    if (threadIdx.x < MSG) bs[threadIdx.x] = b[threadIdx.x];
    __syncthreads();

    int t = blockIdx.x * 256 + threadIdx.x;
    if (t >= NTHREADS) return;

    int eid[EPT], srcn[EPT], dstn[EPT];
#pragma unroll
    for (int i = 0; i < EPT; ++i) {
        eid[i] = t + i * NTHREADS;
        srcn[i] = ei[eid[i]];
        dstn[i] = ei[EDGES + eid[i]];
    }

    float acc[EPT][MSG];
#pragma unroll
    for (int i = 0; i < EPT; ++i)
#pragma unroll
        for (int j = 0; j < MSG; ++j) acc[i][j] = bs[j];

#pragma unroll
    for (int seg = 0; seg < 3; ++seg) {
        // compile-time-selected base pointers (seg unrolled, i unrolled)
        const float4* base[EPT];
#pragma unroll
        for (int i = 0; i < EPT; ++i) {
            if (seg == 0)      base[i] = (const float4*)(node_attr + (size_t)srcn[i] * DF);
            else if (seg == 1) base[i] = (const float4*)(node_attr + (size_t)dstn[i] * DF);
            else               base[i] = (const float4*)(edge_attr + (size_t)eid[i] * DF);
        }
        for (int k4 = 0; k4 < DF / 4; ++k4) {   // rolled: 16 iters
            float4 xv[EPT];
#pragma unroll
            for (int i = 0; i < EPT; ++i) xv[i] = base[i][k4];
            const float* wrow = &Ws[(seg * DF + k4 * 4) * MSG];
#pragma unroll
            for (int cc = 0; cc < 4; ++cc) {
                // W row (k = seg*64 + k4*4 + cc): 20 contiguous floats, 16B-aligned (80B rows)
                float4 w0 = *(const float4*)(wrow + cc * MSG + 0);
                float4 w1 = *(const float4*)(wrow + cc * MSG + 4);
                float4 w2 = *(const float4*)(wrow + cc * MSG + 8);
                float4 w3 = *(const float4*)(wrow + cc * MSG + 12);
                float4 w4 = *(const float4*)(wrow + cc * MSG + 16);
                const float* wf = (const float*)&w0;  // w0..w4 contiguous? no — use per-vec
#pragma unroll
                for (int i = 0; i < EPT; ++i) {
                    const float* xp = (const float*)&xv[i];
                    float x = xp[cc];
                    acc[i][0]  = fmaf(x, w0.x, acc[i][0]);
                    acc[i][1]  = fmaf(x, w0.y, acc[i][1]);
                    acc[i][2]  = fmaf(x, w0.z, acc[i][2]);
                    acc[i][3]  = fmaf(x, w0.w, acc[i][3]);
                    acc[i][4]  = fmaf(x, w1.x, acc[i][4]);
                    acc[i][5]  = fmaf(x, w1.y, acc[i][5]);
                    acc[i][6]  = fmaf(x, w1.z, acc[i][6]);
                    acc[i][7]  = fmaf(x, w1.w, acc[i][7]);
                    acc[i][8]  = fmaf(x, w2.x, acc[i][8]);
                    acc[i][9]  = fmaf(x, w2.y, acc[i][9]);
                    acc[i][10] = fmaf(x, w2.z, acc[i][10]);
                    acc[i][11] = fmaf(x, w2.w, acc[i][11]);
                    acc[i][12] = fmaf(x, w3.x, acc[i][12]);
                    acc[i][13] = fmaf(x, w3.y, acc[i][13]);
                    acc[i][14] = fmaf(x, w3.z, acc[i][14]);
                    acc[i][15] = fmaf(x, w3.w, acc[i][15]);
                    acc[i][16] = fmaf(x, w4.x, acc[i][16]);
                    acc[i][17] = fmaf(x, w4.y, acc[i][17]);
                    acc[i][18] = fmaf(x, w4.z, acc[i][18]);
                    acc[i][19] = fmaf(x, w4.w, acc[i][19]);
                }
            }
        }
    }

#pragma unroll
    for (int i = 0; i < EPT; ++i) {
        float* xr = x1 + (size_t)dstn[i] * MSG;
#pragma unroll
        for (int j = 0; j < MSG; ++j) atomicAdd(xr + j, fmaxf(acc[i][j], 0.0f));
    }
}

// One thread per node: 20 -> relu(W1) -> 20 -> relu(W2) -> 10, atomic into gacc[batch[n]].
__global__ __launch_bounds__(256) void node_kernel(
    const float* __restrict__ x1,  // (N, 20)
    const float* __restrict__ W1, const float* __restrict__ b1, // (20,20)
    const float* __restrict__ W2, const float* __restrict__ b2, // (20,10)
    const int* __restrict__ batch,
    float* __restrict__ gacc)      // (G, 10)
{
    __shared__ float W1s[MSG * MSG], W2s[MSG * HID2], b1s[MSG], b2s[HID2];
    for (int i = threadIdx.x; i < MSG * MSG; i += 256) W1s[i] = W1[i];
    for (int i = threadIdx.x; i < MSG * HID2; i += 256) W2s[i] = W2[i];
    if (threadIdx.x < MSG) b1s[threadIdx.x] = b1[threadIdx.x];
    if (threadIdx.x < HID2) b2s[threadIdx.x] = b2[threadIdx.x];
    __syncthreads();

    int n = blockIdx.x * 256 + threadIdx.x;
    if (n >= NODES) return;

    float h[MSG];
    const float4* xr = (const float4*)(x1 + (size_t)n * MSG);
#pragma unroll
    for (int q = 0; q < 5; ++q) {
        float4 v = xr[q];
        h[q * 4 + 0] = v.x; h[q * 4 + 1] = v.y;
        h[q * 4 + 2] = v.z; h[q * 4 + 3] = v.w;
    }

    float t1[MSG];
#pragma unroll
    for (int j = 0; j < MSG; ++j) t1[j] = b1s[j];
#pragma unroll
    for (int k = 0; k < MSG; ++k)
#pragma unroll
        for (int j = 0; j < MSG; ++j) t1[j] = fmaf(h[k], W1s[k * MSG + j], t1[j]);
#pragma unroll
    for (int j = 0; j < MSG; ++j) t1[j] = fmaxf(t1[j], 0.0f);

    float t2[HID2];
#pragma unroll
    for (int m = 0; m < HID2; ++m) t2[m] = b2s[m];
#pragma unroll
    for (int k = 0; k < MSG; ++k)
#pragma unroll
        for (int m = 0; m < HID2; ++m) t2[m] = fmaf(t1[k], W2s[k * HID2 + m], t2[m]);

    int g = batch[n];
    float* gr = gacc + (size_t)g * HID2;
#pragma unroll
    for (int m = 0; m < HID2; ++m) atomicAdd(gr + m, fmaxf(t2[m], 0.0f));
}

// One thread per graph: 10 -> relu(W3) -> 10 -> W4 -> 1.
__global__ void graph_kernel(
    const float* __restrict__ gacc, // (G, 10)
    const float* __restrict__ W3, const float* __restrict__ b3, // (10,10)
    const float* __restrict__ W4, const float* __restrict__ b4, // (10,1)
    float* __restrict__ out)        // (G, 1)
{
    int g = blockIdx.x * blockDim.x + threadIdx.x;
    if (g >= GRAPHS) return;

    float h[HID2];
#pragma unroll
    for (int m = 0; m < HID2; ++m) h[m] = gacc[(size_t)g * HID2 + m];

    float t[HID2];
#pragma unroll
    for (int j = 0; j < HID2; ++j) {
        float s = b3[j];
#pragma unroll
        for (int k = 0; k < HID2; ++k) s = fmaf(h[k], W3[k * HID2 + j], s);
        t[j] = fmaxf(s, 0.0f);
    }

    float s = b4[0];
#pragma unroll
    for (int k = 0; k < HID2; ++k) s = fmaf(t[k], W4[k], s);
    out[g] = s;
}

extern "C" void kernel_launch(void* const* d_in, const int* in_sizes, int n_in,
                              void* d_out, int out_size, void* d_ws, size_t ws_size,
                              hipStream_t stream) {
    const int*   ei        = (const int*)  d_in[0];
    const float* node_attr = (const float*)d_in[1];
    const float* edge_attr = (const float*)d_in[2];
    const int*   batch     = (const int*)  d_in[3];
    const float* W_mpl     = (const float*)d_in[4];
    const float* b_mpl     = (const float*)d_in[5];
    const float* W1        = (const float*)d_in[6];
    const float* b1        = (const float*)d_in[7];
    const float* W2        = (const float*)d_in[8];
    const float* b2        = (const float*)d_in[9];
    const float* W3        = (const float*)d_in[10];
    const float* b3        = (const float*)d_in[11];
    const float* W4        = (const float*)d_in[12];
    const float* b4        = (const float*)d_in[13];
    float* out = (float*)d_out;

    float* x1   = (float*)d_ws;                  // N*20 floats
    float* gacc = x1 + (size_t)NODES * MSG;      // G*10 floats

    int ztot = NODES * MSG + GRAPHS * HID2;
    hipLaunchKernelGGL(zero_kernel, dim3(2048), dim3(256), 0, stream, x1, ztot);
    hipLaunchKernelGGL(edge_kernel, dim3((NTHREADS + 255) / 256), dim3(256), 0, stream,
                       ei, node_attr, edge_attr, W_mpl, b_mpl, x1);
    hipLaunchKernelGGL(node_kernel, dim3((NODES + 255) / 256), dim3(256), 0, stream,
                       x1, W1, b1, W2, b2, batch, gacc);
    hipLaunchKernelGGL(graph_kernel, dim3(2), dim3(256), 0, stream,
                       gacc, W3, b3, W4, b4, out);
}

// Round 3
// 432.409 us; speedup vs baseline: 2.8127x; 2.8127x over previous
//
#include <hip/hip_runtime.h>

#define DF 64
#define MSG 20
#define HID2 10
#define NODES 50000
#define EDGES 800000
#define GRAPHS 512
#define NB1 ((NODES + 255) / 256)   // 196 blocks for per-node arrays

// 20 FMAs: acc[0..19] += xv * wr[0..19] (wr points into LDS, 16B-aligned)
#define FMA20(acc, xv, wr) do { \
  float4 w0_ = *(const float4*)((wr) + 0);  float4 w1_ = *(const float4*)((wr) + 4); \
  float4 w2_ = *(const float4*)((wr) + 8);  float4 w3_ = *(const float4*)((wr) + 12); \
  float4 w4_ = *(const float4*)((wr) + 16); \
  acc[0]=fmaf(xv,w0_.x,acc[0]);  acc[1]=fmaf(xv,w0_.y,acc[1]);  acc[2]=fmaf(xv,w0_.z,acc[2]);  acc[3]=fmaf(xv,w0_.w,acc[3]); \
  acc[4]=fmaf(xv,w1_.x,acc[4]);  acc[5]=fmaf(xv,w1_.y,acc[5]);  acc[6]=fmaf(xv,w1_.z,acc[6]);  acc[7]=fmaf(xv,w1_.w,acc[7]); \
  acc[8]=fmaf(xv,w2_.x,acc[8]);  acc[9]=fmaf(xv,w2_.y,acc[9]);  acc[10]=fmaf(xv,w2_.z,acc[10]); acc[11]=fmaf(xv,w2_.w,acc[11]); \
  acc[12]=fmaf(xv,w3_.x,acc[12]); acc[13]=fmaf(xv,w3_.y,acc[13]); acc[14]=fmaf(xv,w3_.z,acc[14]); acc[15]=fmaf(xv,w3_.w,acc[15]); \
  acc[16]=fmaf(xv,w4_.x,acc[16]); acc[17]=fmaf(xv,w4_.y,acc[17]); acc[18]=fmaf(xv,w4_.z,acc[18]); acc[19]=fmaf(xv,w4_.w,acc[19]); \
} while (0)

__global__ __launch_bounds__(256) void zero2_kernel(int* __restrict__ cnt, float* __restrict__ g) {
    int i = blockIdx.x * 256 + threadIdx.x;
    int st = gridDim.x * 256;
    for (int k = i; k < NODES; k += st) cnt[k] = 0;
    for (int k = i; k < GRAPHS * HID2; k += st) g[k] = 0.0f;
}

__global__ __launch_bounds__(256) void count_kernel(const int* __restrict__ ei, int* __restrict__ cnt) {
    int e = blockIdx.x * 256 + threadIdx.x;
    if (e < EDGES) atomicAdd(&cnt[ei[EDGES + e]], 1);
}

// Block-wise exclusive scan (Hillis-Steele in LDS). outx[i] = exclusive, bsum[blk] = block total.
__global__ __launch_bounds__(256) void scan_block(const int* __restrict__ in, int* __restrict__ outx,
                                                  int* __restrict__ bsum, int n) {
    __shared__ int s[256];
    int t = threadIdx.x, i = blockIdx.x * 256 + t;
    int v = (i < n) ? in[i] : 0;
    s[t] = v; __syncthreads();
    for (int off = 1; off < 256; off <<= 1) {
        int x = (t >= off) ? s[t - off] : 0;
        __syncthreads();
        s[t] += x; __syncthreads();
    }
    if (i < n) outx[i] = s[t] - v;
    if (t == 255 && bsum != nullptr) bsum[blockIdx.x] = s[255];
}

__global__ __launch_bounds__(256) void scan_fixup(int* __restrict__ rs, int* __restrict__ cur,
                                                  const int* __restrict__ bscan) {
    int i = blockIdx.x * 256 + threadIdx.x;
    if (i < NODES) {
        int r = rs[i] + bscan[blockIdx.x];
        rs[i] = r;
        cur[i] = r;
    }
    if (i == 0) rs[NODES] = EDGES;
}

__global__ __launch_bounds__(256) void fill_kernel(const int* __restrict__ ei, int* __restrict__ cur,
                                                   int* __restrict__ elist) {
    int e = blockIdx.x * 256 + threadIdx.x;
    if (e < EDGES) {
        int p = atomicAdd(&cur[ei[EDGES + e]], 1);
        elist[p] = e;
    }
}

// Pe[e] = edge_attr[e] @ W[128:192] + b   (streaming, 1 thread/edge)
__global__ __launch_bounds__(256) void pe_kernel(const float* __restrict__ edge_attr,
                                                 const float* __restrict__ W, const float* __restrict__ b,
                                                 float* __restrict__ Pe) {
    __shared__ float Ws[DF * MSG];
    __shared__ float bs[MSG];
    for (int i = threadIdx.x; i < DF * MSG; i += 256) Ws[i] = W[2 * DF * MSG + i];
    if (threadIdx.x < MSG) bs[threadIdx.x] = b[threadIdx.x];
    __syncthreads();

    int e = blockIdx.x * 256 + threadIdx.x;
    if (e >= EDGES) return;

    const float4* er = (const float4*)(edge_attr + (size_t)e * DF);
    float4 x[16];
#pragma unroll
    for (int i = 0; i < 16; ++i) x[i] = er[i];

    float acc[MSG];
#pragma unroll
    for (int j = 0; j < MSG; ++j) acc[j] = bs[j];

#pragma unroll
    for (int k4 = 0; k4 < 16; ++k4) {
        const float* xp = (const float*)&x[k4];
#pragma unroll
        for (int cc = 0; cc < 4; ++cc) FMA20(acc, xp[cc], &Ws[(k4 * 4 + cc) * MSG]);
    }

    float4* po = (float4*)(Pe + (size_t)e * MSG);
    po[0] = make_float4(acc[0],  acc[1],  acc[2],  acc[3]);
    po[1] = make_float4(acc[4],  acc[5],  acc[6],  acc[7]);
    po[2] = make_float4(acc[8],  acc[9],  acc[10], acc[11]);
    po[3] = make_float4(acc[12], acc[13], acc[14], acc[15]);
    po[4] = make_float4(acc[16], acc[17], acc[18], acc[19]);
}

// Ps[n] = node_attr[n] @ W[0:64];  Pd[n] = node_attr[n] @ W[64:128]   (no bias)
__global__ __launch_bounds__(256) void pn_kernel(const float* __restrict__ node_attr,
                                                 const float* __restrict__ W,
                                                 float* __restrict__ Ps, float* __restrict__ Pd) {
    __shared__ float Wss[DF * MSG];
    __shared__ float Wds[DF * MSG];
    for (int i = threadIdx.x; i < DF * MSG; i += 256) {
        Wss[i] = W[i];
        Wds[i] = W[DF * MSG + i];
    }
    __syncthreads();

    int n = blockIdx.x * 256 + threadIdx.x;
    if (n >= NODES) return;

    const float4* nr = (const float4*)(node_attr + (size_t)n * DF);
    float4 x[16];
#pragma unroll
    for (int i = 0; i < 16; ++i) x[i] = nr[i];

    float as[MSG], ad[MSG];
#pragma unroll
    for (int j = 0; j < MSG; ++j) { as[j] = 0.0f; ad[j] = 0.0f; }

#pragma unroll
    for (int k4 = 0; k4 < 16; ++k4) {
        const float* xp = (const float*)&x[k4];
#pragma unroll
        for (int cc = 0; cc < 4; ++cc) {
            FMA20(as, xp[cc], &Wss[(k4 * 4 + cc) * MSG]);
            FMA20(ad, xp[cc], &Wds[(k4 * 4 + cc) * MSG]);
        }
    }

    float4* po = (float4*)(Ps + (size_t)n * MSG);
    po[0] = make_float4(as[0],  as[1],  as[2],  as[3]);
    po[1] = make_float4(as[4],  as[5],  as[6],  as[7]);
    po[2] = make_float4(as[8],  as[9],  as[10], as[11]);
    po[3] = make_float4(as[12], as[13], as[14], as[15]);
    po[4] = make_float4(as[16], as[17], as[18], as[19]);
    float4* qo = (float4*)(Pd + (size_t)n * MSG);
    qo[0] = make_float4(ad[0],  ad[1],  ad[2],  ad[3]);
    qo[1] = make_float4(ad[4],  ad[5],  ad[6],  ad[7]);
    qo[2] = make_float4(ad[8],  ad[9],  ad[10], ad[11]);
    qo[3] = make_float4(ad[12], ad[13], ad[14], ad[15]);
    qo[4] = make_float4(ad[16], ad[17], ad[18], ad[19]);
}

// Node-centric aggregate: 4 lanes per node pull in-edges via CSR, sum relu(Pe+Ps+Pd),
// quad shfl-reduce, then 20->20->10 MLP and atomic into gacc[batch[n]].
__global__ __launch_bounds__(256) void agg_kernel(const int* __restrict__ ei, const int* __restrict__ rs,
                                                  const int* __restrict__ elist,
                                                  const float* __restrict__ Pe, const float* __restrict__ Ps,
                                                  const float* __restrict__ Pd,
                                                  const float* __restrict__ W1, const float* __restrict__ b1,
                                                  const float* __restrict__ W2, const float* __restrict__ b2,
                                                  const int* __restrict__ batch, float* __restrict__ gacc) {
    __shared__ float W1s[MSG * MSG], W2s[MSG * HID2], b1s[MSG], b2s[HID2];
    for (int i = threadIdx.x; i < MSG * MSG; i += 256) W1s[i] = W1[i];
    for (int i = threadIdx.x; i < MSG * HID2; i += 256) W2s[i] = W2[i];
    if (threadIdx.x < MSG) b1s[threadIdx.x] = b1[threadIdx.x];
    if (threadIdx.x < HID2) b2s[threadIdx.x] = b2[threadIdx.x];
    __syncthreads();

    int t = threadIdx.x;
    int node = blockIdx.x * 64 + (t >> 2);
    int lane = t & 3;

    float acc[MSG];
#pragma unroll
    for (int j = 0; j < MSG; ++j) acc[j] = 0.0f;

    if (node < NODES) {
        int s0 = rs[node];
        int deg = rs[node + 1] - s0;

        float pd[MSG];
        const float4* pdr = (const float4*)(Pd + (size_t)node * MSG);
#pragma unroll
        for (int q = 0; q < 5; ++q) {
            float4 v = pdr[q];
            pd[q * 4 + 0] = v.x; pd[q * 4 + 1] = v.y; pd[q * 4 + 2] = v.z; pd[q * 4 + 3] = v.w;
        }

        for (int i = lane; i < deg; i += 4) {
            int e = elist[s0 + i];
            int src = ei[e];
            const float4* pe = (const float4*)(Pe + (size_t)e * MSG);
            const float4* ps = (const float4*)(Ps + (size_t)src * MSG);
#pragma unroll
            for (int q = 0; q < 5; ++q) {
                float4 a = pe[q];
                float4 c = ps[q];
                acc[q * 4 + 0] += fmaxf(a.x + c.x + pd[q * 4 + 0], 0.0f);
                acc[q * 4 + 1] += fmaxf(a.y + c.y + pd[q * 4 + 1], 0.0f);
                acc[q * 4 + 2] += fmaxf(a.z + c.z + pd[q * 4 + 2], 0.0f);
                acc[q * 4 + 3] += fmaxf(a.w + c.w + pd[q * 4 + 3], 0.0f);
            }
        }
    }

#pragma unroll
    for (int j = 0; j < MSG; ++j) acc[j] += __shfl_xor(acc[j], 1);
#pragma unroll
    for (int j = 0; j < MSG; ++j) acc[j] += __shfl_xor(acc[j], 2);

    if (node < NODES && lane == 0) {
        float t1[MSG];
#pragma unroll
        for (int j = 0; j < MSG; ++j) {
            float s = b1s[j];
#pragma unroll
            for (int k = 0; k < MSG; ++k) s = fmaf(acc[k], W1s[k * MSG + j], s);
            t1[j] = fmaxf(s, 0.0f);
        }
        float t2[HID2];
#pragma unroll
        for (int m = 0; m < HID2; ++m) {
            float s = b2s[m];
#pragma unroll
            for (int k = 0; k < MSG; ++k) s = fmaf(t1[k], W2s[k * HID2 + m], s);
            t2[m] = fmaxf(s, 0.0f);
        }
        int g = batch[node];
        float* gr = gacc + (size_t)g * HID2;
#pragma unroll
        for (int m = 0; m < HID2; ++m) atomicAdd(gr + m, t2[m]);
    }
}

__global__ void graph_kernel(const float* __restrict__ gacc,
                             const float* __restrict__ W3, const float* __restrict__ b3,
                             const float* __restrict__ W4, const float* __restrict__ b4,
                             float* __restrict__ out) {
    int g = blockIdx.x * blockDim.x + threadIdx.x;
    if (g >= GRAPHS) return;

    float h[HID2];
#pragma unroll
    for (int m = 0; m < HID2; ++m) h[m] = gacc[(size_t)g * HID2 + m];

    float t[HID2];
#pragma unroll
    for (int j = 0; j < HID2; ++j) {
        float s = b3[j];
#pragma unroll
        for (int k = 0; k < HID2; ++k) s = fmaf(h[k], W3[k * HID2 + j], s);
        t[j] = fmaxf(s, 0.0f);
    }
    float s = b4[0];
#pragma unroll
    for (int k = 0; k < HID2; ++k) s = fmaf(t[k], W4[k], s);
    out[g] = s;
}

extern "C" void kernel_launch(void* const* d_in, const int* in_sizes, int n_in,
                              void* d_out, int out_size, void* d_ws, size_t ws_size,
                              hipStream_t stream) {
    const int*   ei        = (const int*)  d_in[0];
    const float* node_attr = (const float*)d_in[1];
    const float* edge_attr = (const float*)d_in[2];
    const int*   batch     = (const int*)  d_in[3];
    const float* W_mpl     = (const float*)d_in[4];
    const float* b_mpl     = (const float*)d_in[5];
    const float* W1        = (const float*)d_in[6];
    const float* b1        = (const float*)d_in[7];
    const float* W2        = (const float*)d_in[8];
    const float* b2        = (const float*)d_in[9];
    const float* W3        = (const float*)d_in[10];
    const float* b3        = (const float*)d_in[11];
    const float* W4        = (const float*)d_in[12];
    const float* b4        = (const float*)d_in[13];
    float* out = (float*)d_out;

    // workspace layout
    float* Pe   = (float*)d_ws;                          // E*20 floats (64 MB)
    float* Ps   = Pe + (size_t)EDGES * MSG;              // N*20 (4 MB)
    float* Pd   = Ps + (size_t)NODES * MSG;              // N*20 (4 MB)
    float* gacc = Pd + (size_t)NODES * MSG;              // G*10
    int* cnt    = (int*)(gacc + GRAPHS * HID2);          // N (padded 50176)
    int* rs     = cnt + 50176;                           // N+1 (padded)
    int* cur    = rs + 50176;                            // N (padded)
    int* bsum   = cur + 50176;                           // 256
    int* bscan  = bsum + 256;                            // 256
    int* elist  = bscan + 256;                           // E

    int egrid = (EDGES + 255) / 256;   // 3125
    int ngrid = NB1;                   // 196

    hipLaunchKernelGGL(zero2_kernel, dim3(256), dim3(256), 0, stream, cnt, gacc);
    hipLaunchKernelGGL(count_kernel, dim3(egrid), dim3(256), 0, stream, ei, cnt);
    hipLaunchKernelGGL(scan_block, dim3(ngrid), dim3(256), 0, stream, cnt, rs, bsum, NODES);
    hipLaunchKernelGGL(scan_block, dim3(1), dim3(256), 0, stream, bsum, bscan, (int*)nullptr, NB1);
    hipLaunchKernelGGL(scan_fixup, dim3(ngrid), dim3(256), 0, stream, rs, cur, bscan);
    hipLaunchKernelGGL(fill_kernel, dim3(egrid), dim3(256), 0, stream, ei, cur, elist);
    hipLaunchKernelGGL(pe_kernel, dim3(egrid), dim3(256), 0, stream, edge_attr, W_mpl, b_mpl, Pe);
    hipLaunchKernelGGL(pn_kernel, dim3(ngrid), dim3(256), 0, stream, node_attr, W_mpl, Ps, Pd);
    hipLaunchKernelGGL(agg_kernel, dim3((NODES + 63) / 64), dim3(256), 0, stream,
                       ei, rs, elist, Pe, Ps, Pd, W1, b1, W2, b2, batch, gacc);
    hipLaunchKernelGGL(graph_kernel, dim3(2), dim3(256), 0, stream, gacc, W3, b3, W4, b4, out);
}

// Round 4
// 326.665 us; speedup vs baseline: 3.7231x; 1.3237x over previous
//
#include <hip/hip_runtime.h>

#define DF 64
#define MSG 20
#define HID2 10
#define NODES 50000
#define EDGES 800000
#define GRAPHS 512
#define NB1 ((NODES + 255) / 256)   // 196 blocks for per-node arrays

// 20 FMAs: acc[0..19] += xv * wr[0..19] (wr points into LDS, 16B-aligned)
#define FMA20(acc, xv, wr) do { \
  float4 w0_ = *(const float4*)((wr) + 0);  float4 w1_ = *(const float4*)((wr) + 4); \
  float4 w2_ = *(const float4*)((wr) + 8);  float4 w3_ = *(const float4*)((wr) + 12); \
  float4 w4_ = *(const float4*)((wr) + 16); \
  acc[0]=fmaf(xv,w0_.x,acc[0]);  acc[1]=fmaf(xv,w0_.y,acc[1]);  acc[2]=fmaf(xv,w0_.z,acc[2]);  acc[3]=fmaf(xv,w0_.w,acc[3]); \
  acc[4]=fmaf(xv,w1_.x,acc[4]);  acc[5]=fmaf(xv,w1_.y,acc[5]);  acc[6]=fmaf(xv,w1_.z,acc[6]);  acc[7]=fmaf(xv,w1_.w,acc[7]); \
  acc[8]=fmaf(xv,w2_.x,acc[8]);  acc[9]=fmaf(xv,w2_.y,acc[9]);  acc[10]=fmaf(xv,w2_.z,acc[10]); acc[11]=fmaf(xv,w2_.w,acc[11]); \
  acc[12]=fmaf(xv,w3_.x,acc[12]); acc[13]=fmaf(xv,w3_.y,acc[13]); acc[14]=fmaf(xv,w3_.z,acc[14]); acc[15]=fmaf(xv,w3_.w,acc[15]); \
  acc[16]=fmaf(xv,w4_.x,acc[16]); acc[17]=fmaf(xv,w4_.y,acc[17]); acc[18]=fmaf(xv,w4_.z,acc[18]); acc[19]=fmaf(xv,w4_.w,acc[19]); \
} while (0)

__global__ __launch_bounds__(256) void zero2_kernel(int* __restrict__ cnt, float* __restrict__ g) {
    int i = blockIdx.x * 256 + threadIdx.x;
    int st = gridDim.x * 256;
    for (int k = i; k < NODES; k += st) cnt[k] = 0;
    for (int k = i; k < GRAPHS * HID2; k += st) g[k] = 0.0f;
}

__global__ __launch_bounds__(256) void count_kernel(const int* __restrict__ ei, int* __restrict__ cnt) {
    int e = blockIdx.x * 256 + threadIdx.x;
    if (e < EDGES) atomicAdd(&cnt[ei[EDGES + e]], 1);
}

// Block-wise exclusive scan (Hillis-Steele in LDS). outx[i] = exclusive, bsum[blk] = block total.
__global__ __launch_bounds__(256) void scan_block(const int* __restrict__ in, int* __restrict__ outx,
                                                  int* __restrict__ bsum, int n) {
    __shared__ int s[256];
    int t = threadIdx.x, i = blockIdx.x * 256 + t;
    int v = (i < n) ? in[i] : 0;
    s[t] = v; __syncthreads();
    for (int off = 1; off < 256; off <<= 1) {
        int x = (t >= off) ? s[t - off] : 0;
        __syncthreads();
        s[t] += x; __syncthreads();
    }
    if (i < n) outx[i] = s[t] - v;
    if (t == 255 && bsum != nullptr) bsum[blockIdx.x] = s[255];
}

__global__ __launch_bounds__(256) void scan_fixup(int* __restrict__ rs, int* __restrict__ cur,
                                                  const int* __restrict__ bscan) {
    int i = blockIdx.x * 256 + threadIdx.x;
    if (i < NODES) {
        int r = rs[i] + bscan[blockIdx.x];
        rs[i] = r;
        cur[i] = r;
    }
    if (i == 0) rs[NODES] = EDGES;
}

// Ps[n] = node_attr[n] @ W[0:64];  Pd[n] = node_attr[n] @ W[64:128]   (no bias)
__global__ __launch_bounds__(256) void pn_kernel(const float* __restrict__ node_attr,
                                                 const float* __restrict__ W,
                                                 float* __restrict__ Ps, float* __restrict__ Pd) {
    __shared__ float Wss[DF * MSG];
    __shared__ float Wds[DF * MSG];
    for (int i = threadIdx.x; i < DF * MSG; i += 256) {
        Wss[i] = W[i];
        Wds[i] = W[DF * MSG + i];
    }
    __syncthreads();

    int n = blockIdx.x * 256 + threadIdx.x;
    if (n >= NODES) return;

    const float4* nr = (const float4*)(node_attr + (size_t)n * DF);

    float as[MSG], ad[MSG];
#pragma unroll
    for (int j = 0; j < MSG; ++j) { as[j] = 0.0f; ad[j] = 0.0f; }

#pragma unroll
    for (int c4 = 0; c4 < 4; ++c4) {          // 4 chunks of 4 float4s
        float4 x[4];
#pragma unroll
        for (int q = 0; q < 4; ++q) x[q] = nr[c4 * 4 + q];
#pragma unroll
        for (int q = 0; q < 4; ++q) {
            const float* xp = (const float*)&x[q];
#pragma unroll
            for (int cc = 0; cc < 4; ++cc) {
                int k = (c4 * 4 + q) * 4 + cc;
                FMA20(as, xp[cc], &Wss[k * MSG]);
                FMA20(ad, xp[cc], &Wds[k * MSG]);
            }
        }
    }

    float4* po = (float4*)(Ps + (size_t)n * MSG);
    po[0] = make_float4(as[0],  as[1],  as[2],  as[3]);
    po[1] = make_float4(as[4],  as[5],  as[6],  as[7]);
    po[2] = make_float4(as[8],  as[9],  as[10], as[11]);
    po[3] = make_float4(as[12], as[13], as[14], as[15]);
    po[4] = make_float4(as[16], as[17], as[18], as[19]);
    float4* qo = (float4*)(Pd + (size_t)n * MSG);
    qo[0] = make_float4(ad[0],  ad[1],  ad[2],  ad[3]);
    qo[1] = make_float4(ad[4],  ad[5],  ad[6],  ad[7]);
    qo[2] = make_float4(ad[8],  ad[9],  ad[10], ad[11]);
    qo[3] = make_float4(ad[12], ad[13], ad[14], ad[15]);
    qo[4] = make_float4(ad[16], ad[17], ad[18], ad[19]);
}

// Per edge: row = edge_attr[e] @ W[128:192] + b + Ps[src], written to CSR slot
// p = atomicAdd(cur[dst]). Downstream agg reads PeP purely sequentially.
__global__ __launch_bounds__(256) void pe_perm_kernel(const int* __restrict__ ei,
                                                      const float* __restrict__ edge_attr,
                                                      const float* __restrict__ W, const float* __restrict__ b,
                                                      const float* __restrict__ Ps,
                                                      int* __restrict__ cur,
                                                      float* __restrict__ PeP) {
    __shared__ float Ws[DF * MSG];
    __shared__ float bs[MSG];
    for (int i = threadIdx.x; i < DF * MSG; i += 256) Ws[i] = W[2 * DF * MSG + i];
    if (threadIdx.x < MSG) bs[threadIdx.x] = b[threadIdx.x];
    __syncthreads();

    int e = blockIdx.x * 256 + threadIdx.x;
    if (e >= EDGES) return;

    int src = ei[e];
    int dst = ei[EDGES + e];
    int p = atomicAdd(&cur[dst], 1);          // issue early; result needed only at the end

    const float4* er = (const float4*)(edge_attr + (size_t)e * DF);
    const float4* psr = (const float4*)(Ps + (size_t)src * MSG);

    float acc[MSG];
#pragma unroll
    for (int j = 0; j < MSG; ++j) acc[j] = bs[j];

#pragma unroll
    for (int c4 = 0; c4 < 4; ++c4) {          // 4 chunks of 4 float4s -> lower VGPR pressure
        float4 x[4];
#pragma unroll
        for (int q = 0; q < 4; ++q) x[q] = er[c4 * 4 + q];
#pragma unroll
        for (int q = 0; q < 4; ++q) {
            const float* xp = (const float*)&x[q];
#pragma unroll
            for (int cc = 0; cc < 4; ++cc)
                FMA20(acc, xp[cc], &Ws[((c4 * 4 + q) * 4 + cc) * MSG]);
        }
    }

    // add Ps[src] (random 80B read from 4MB L2-resident table)
    float4 s0 = psr[0], s1 = psr[1], s2 = psr[2], s3 = psr[3], s4 = psr[4];
    acc[0] += s0.x;  acc[1] += s0.y;  acc[2] += s0.z;  acc[3] += s0.w;
    acc[4] += s1.x;  acc[5] += s1.y;  acc[6] += s1.z;  acc[7] += s1.w;
    acc[8] += s2.x;  acc[9] += s2.y;  acc[10] += s2.z; acc[11] += s2.w;
    acc[12] += s3.x; acc[13] += s3.y; acc[14] += s3.z; acc[15] += s3.w;
    acc[16] += s4.x; acc[17] += s4.y; acc[18] += s4.z; acc[19] += s4.w;

    float4* po = (float4*)(PeP + (size_t)p * MSG);
    po[0] = make_float4(acc[0],  acc[1],  acc[2],  acc[3]);
    po[1] = make_float4(acc[4],  acc[5],  acc[6],  acc[7]);
    po[2] = make_float4(acc[8],  acc[9],  acc[10], acc[11]);
    po[3] = make_float4(acc[12], acc[13], acc[14], acc[15]);
    po[4] = make_float4(acc[16], acc[17], acc[18], acc[19]);
}

// Node-centric aggregate: 4 lanes per node stream contiguous CSR rows of PeP,
// acc += relu(row + Pd[node]); quad shfl-reduce; 20->20->10 MLP; atomic into gacc.
__global__ __launch_bounds__(256) void agg_kernel(const int* __restrict__ rs,
                                                  const float* __restrict__ PeP,
                                                  const float* __restrict__ Pd,
                                                  const float* __restrict__ W1, const float* __restrict__ b1,
                                                  const float* __restrict__ W2, const float* __restrict__ b2,
                                                  const int* __restrict__ batch, float* __restrict__ gacc) {
    __shared__ float W1s[MSG * MSG], W2s[MSG * HID2], b1s[MSG], b2s[HID2];
    for (int i = threadIdx.x; i < MSG * MSG; i += 256) W1s[i] = W1[i];
    for (int i = threadIdx.x; i < MSG * HID2; i += 256) W2s[i] = W2[i];
    if (threadIdx.x < MSG) b1s[threadIdx.x] = b1[threadIdx.x];
    if (threadIdx.x < HID2) b2s[threadIdx.x] = b2[threadIdx.x];
    __syncthreads();

    int t = threadIdx.x;
    int node = blockIdx.x * 64 + (t >> 2);
    int lane = t & 3;

    float acc[MSG];
#pragma unroll
    for (int j = 0; j < MSG; ++j) acc[j] = 0.0f;

    if (node < NODES) {
        int s0 = rs[node];
        int deg = rs[node + 1] - s0;

        float pd[MSG];
        const float4* pdr = (const float4*)(Pd + (size_t)node * MSG);
#pragma unroll
        for (int q = 0; q < 5; ++q) {
            float4 v = pdr[q];
            pd[q * 4 + 0] = v.x; pd[q * 4 + 1] = v.y; pd[q * 4 + 2] = v.z; pd[q * 4 + 3] = v.w;
        }

        for (int i = lane; i < deg; i += 4) {
            const float4* pe = (const float4*)(PeP + (size_t)(s0 + i) * MSG);
#pragma unroll
            for (int q = 0; q < 5; ++q) {
                float4 a = pe[q];
                acc[q * 4 + 0] += fmaxf(a.x + pd[q * 4 + 0], 0.0f);
                acc[q * 4 + 1] += fmaxf(a.y + pd[q * 4 + 1], 0.0f);
                acc[q * 4 + 2] += fmaxf(a.z + pd[q * 4 + 2], 0.0f);
                acc[q * 4 + 3] += fmaxf(a.w + pd[q * 4 + 3], 0.0f);
            }
        }
    }

#pragma unroll
    for (int j = 0; j < MSG; ++j) acc[j] += __shfl_xor(acc[j], 1);
#pragma unroll
    for (int j = 0; j < MSG; ++j) acc[j] += __shfl_xor(acc[j], 2);

    if (node < NODES && lane == 0) {
        float t1[MSG];
#pragma unroll
        for (int j = 0; j < MSG; ++j) t1[j] = b1s[j];
#pragma unroll
        for (int k = 0; k < MSG; ++k)
#pragma unroll
            for (int j = 0; j < MSG; ++j) t1[j] = fmaf(acc[k], W1s[k * MSG + j], t1[j]);
#pragma unroll
        for (int j = 0; j < MSG; ++j) t1[j] = fmaxf(t1[j], 0.0f);

        float t2[HID2];
#pragma unroll
        for (int m = 0; m < HID2; ++m) t2[m] = b2s[m];
#pragma unroll
        for (int k = 0; k < MSG; ++k)
#pragma unroll
            for (int m = 0; m < HID2; ++m) t2[m] = fmaf(t1[k], W2s[k * HID2 + m], t2[m]);

        int g = batch[node];
        float* gr = gacc + (size_t)g * HID2;
#pragma unroll
        for (int m = 0; m < HID2; ++m) atomicAdd(gr + m, fmaxf(t2[m], 0.0f));
    }
}

__global__ void graph_kernel(const float* __restrict__ gacc,
                             const float* __restrict__ W3, const float* __restrict__ b3,
                             const float* __restrict__ W4, const float* __restrict__ b4,
                             float* __restrict__ out) {
    int g = blockIdx.x * blockDim.x + threadIdx.x;
    if (g >= GRAPHS) return;

    float h[HID2];
#pragma unroll
    for (int m = 0; m < HID2; ++m) h[m] = gacc[(size_t)g * HID2 + m];

    float t[HID2];
#pragma unroll
    for (int j = 0; j < HID2; ++j) {
        float s = b3[j];
#pragma unroll
        for (int k = 0; k < HID2; ++k) s = fmaf(h[k], W3[k * HID2 + j], s);
        t[j] = fmaxf(s, 0.0f);
    }
    float s = b4[0];
#pragma unroll
    for (int k = 0; k < HID2; ++k) s = fmaf(t[k], W4[k], s);
    out[g] = s;
}

extern "C" void kernel_launch(void* const* d_in, const int* in_sizes, int n_in,
                              void* d_out, int out_size, void* d_ws, size_t ws_size,
                              hipStream_t stream) {
    const int*   ei        = (const int*)  d_in[0];
    const float* node_attr = (const float*)d_in[1];
    const float* edge_attr = (const float*)d_in[2];
    const int*   batch     = (const int*)  d_in[3];
    const float* W_mpl     = (const float*)d_in[4];
    const float* b_mpl     = (const float*)d_in[5];
    const float* W1        = (const float*)d_in[6];
    const float* b1        = (const float*)d_in[7];
    const float* W2        = (const float*)d_in[8];
    const float* b2        = (const float*)d_in[9];
    const float* W3        = (const float*)d_in[10];
    const float* b3        = (const float*)d_in[11];
    const float* W4        = (const float*)d_in[12];
    const float* b4        = (const float*)d_in[13];
    float* out = (float*)d_out;

    // workspace layout
    float* PeP  = (float*)d_ws;                          // E*20 floats (64 MB), CSR-ordered
    float* Ps   = PeP + (size_t)EDGES * MSG;             // N*20 (4 MB)
    float* Pd   = Ps + (size_t)NODES * MSG;              // N*20 (4 MB)
    float* gacc = Pd + (size_t)NODES * MSG;              // G*10
    int* cnt    = (int*)(gacc + GRAPHS * HID2);          // N (padded 50176)
    int* rs     = cnt + 50176;                           // N+1 (padded)
    int* cur    = rs + 50176;                            // N (padded)
    int* bsum   = cur + 50176;                           // 256
    int* bscan  = bsum + 256;                            // 256

    int egrid = (EDGES + 255) / 256;   // 3125
    int ngrid = NB1;                   // 196

    hipLaunchKernelGGL(zero2_kernel, dim3(256), dim3(256), 0, stream, cnt, gacc);
    hipLaunchKernelGGL(count_kernel, dim3(egrid), dim3(256), 0, stream, ei, cnt);
    hipLaunchKernelGGL(scan_block, dim3(ngrid), dim3(256), 0, stream, cnt, rs, bsum, NODES);
    hipLaunchKernelGGL(scan_block, dim3(1), dim3(256), 0, stream, bsum, bscan, (int*)nullptr, NB1);
    hipLaunchKernelGGL(scan_fixup, dim3(ngrid), dim3(256), 0, stream, rs, cur, bscan);
    hipLaunchKernelGGL(pn_kernel, dim3(ngrid), dim3(256), 0, stream, node_attr, W_mpl, Ps, Pd);
    hipLaunchKernelGGL(pe_perm_kernel, dim3(egrid), dim3(256), 0, stream,
                       ei, edge_attr, W_mpl, b_mpl, Ps, cur, PeP);
    hipLaunchKernelGGL(agg_kernel, dim3((NODES + 63) / 64), dim3(256), 0, stream,
                       rs, PeP, Pd, W1, b1, W2, b2, batch, gacc);
    hipLaunchKernelGGL(graph_kernel, dim3(2), dim3(256), 0, stream, gacc, W3, b3, W4, b4, out);
}

// Round 5
// 298.887 us; speedup vs baseline: 4.0691x; 1.0929x over previous
//
#include <hip/hip_runtime.h>
#include <hip/hip_fp16.h>

#define DF 64
#define MSG 20
#define HID2 10
#define NODES 50000
#define EDGES 800000
#define GRAPHS 512
#define RSTRIDE 32   // halves per padded row = 64 bytes, one cache line
#define NB1 ((NODES + 255) / 256)   // 196

// 20 FMAs: acc[0..19] += xv * wr[0..19] (wr points into LDS, 16B-aligned)
#define FMA20(acc, xv, wr) do { \
  float4 w0_ = *(const float4*)((wr) + 0);  float4 w1_ = *(const float4*)((wr) + 4); \
  float4 w2_ = *(const float4*)((wr) + 8);  float4 w3_ = *(const float4*)((wr) + 12); \
  float4 w4_ = *(const float4*)((wr) + 16); \
  acc[0]=fmaf(xv,w0_.x,acc[0]);  acc[1]=fmaf(xv,w0_.y,acc[1]);  acc[2]=fmaf(xv,w0_.z,acc[2]);  acc[3]=fmaf(xv,w0_.w,acc[3]); \
  acc[4]=fmaf(xv,w1_.x,acc[4]);  acc[5]=fmaf(xv,w1_.y,acc[5]);  acc[6]=fmaf(xv,w1_.z,acc[6]);  acc[7]=fmaf(xv,w1_.w,acc[7]); \
  acc[8]=fmaf(xv,w2_.x,acc[8]);  acc[9]=fmaf(xv,w2_.y,acc[9]);  acc[10]=fmaf(xv,w2_.z,acc[10]); acc[11]=fmaf(xv,w2_.w,acc[11]); \
  acc[12]=fmaf(xv,w3_.x,acc[12]); acc[13]=fmaf(xv,w3_.y,acc[13]); acc[14]=fmaf(xv,w3_.z,acc[14]); acc[15]=fmaf(xv,w3_.w,acc[15]); \
  acc[16]=fmaf(xv,w4_.x,acc[16]); acc[17]=fmaf(xv,w4_.y,acc[17]); acc[18]=fmaf(xv,w4_.z,acc[18]); acc[19]=fmaf(xv,w4_.w,acc[19]); \
} while (0)

__global__ __launch_bounds__(256) void zero2_kernel(int* __restrict__ cnt, float* __restrict__ g) {
    int i = blockIdx.x * 256 + threadIdx.x;
    int st = gridDim.x * 256;
    for (int k = i; k < NODES; k += st) cnt[k] = 0;
    for (int k = i; k < GRAPHS * HID2; k += st) g[k] = 0.0f;
}

__global__ __launch_bounds__(256) void count_kernel(const int* __restrict__ ei, int* __restrict__ cnt) {
    int e = blockIdx.x * 256 + threadIdx.x;
    if (e < EDGES) atomicAdd(&cnt[ei[EDGES + e]], 1);
}

// Block-wise exclusive scan (Hillis-Steele in LDS). outx[i] = exclusive, bsum[blk] = block total.
__global__ __launch_bounds__(256) void scan_block(const int* __restrict__ in, int* __restrict__ outx,
                                                  int* __restrict__ bsum, int n) {
    __shared__ int s[256];
    int t = threadIdx.x, i = blockIdx.x * 256 + t;
    int v = (i < n) ? in[i] : 0;
    s[t] = v; __syncthreads();
    for (int off = 1; off < 256; off <<= 1) {
        int x = (t >= off) ? s[t - off] : 0;
        __syncthreads();
        s[t] += x; __syncthreads();
    }
    if (i < n) outx[i] = s[t] - v;
    if (t == 255 && bsum != nullptr) bsum[blockIdx.x] = s[255];
}

__global__ __launch_bounds__(256) void scan_fixup(int* __restrict__ rs, int* __restrict__ cur,
                                                  const int* __restrict__ bscan) {
    int i = blockIdx.x * 256 + threadIdx.x;
    if (i < NODES) {
        int r = rs[i] + bscan[blockIdx.x];
        rs[i] = r;
        cur[i] = r;
    }
    if (i == 0) rs[NODES] = EDGES;
}

__device__ __forceinline__ void store_row_h(__half* dst, const float* acc) {
    union { __half2 h2[16]; uint4 q[4]; } u;
#pragma unroll
    for (int i = 0; i < 10; ++i) u.h2[i] = __floats2half2_rn(acc[2 * i], acc[2 * i + 1]);
#pragma unroll
    for (int i = 10; i < 16; ++i) u.h2[i] = __floats2half2_rn(0.0f, 0.0f);
    uint4* po = (uint4*)dst;
    po[0] = u.q[0]; po[1] = u.q[1]; po[2] = u.q[2]; po[3] = u.q[3];
}

// Ps[n] = node_attr[n] @ W[0:64];  Pd[n] = node_attr[n] @ W[64:128]  (fp16, 64B rows)
__global__ __launch_bounds__(256) void pn_kernel(const float* __restrict__ node_attr,
                                                 const float* __restrict__ W,
                                                 __half* __restrict__ Ps, __half* __restrict__ Pd) {
    __shared__ float Wss[DF * MSG];
    __shared__ float Wds[DF * MSG];
    for (int i = threadIdx.x; i < DF * MSG; i += 256) {
        Wss[i] = W[i];
        Wds[i] = W[DF * MSG + i];
    }
    __syncthreads();

    int n = blockIdx.x * 256 + threadIdx.x;
    if (n >= NODES) return;

    const float4* nr = (const float4*)(node_attr + (size_t)n * DF);

    float as[MSG], ad[MSG];
#pragma unroll
    for (int j = 0; j < MSG; ++j) { as[j] = 0.0f; ad[j] = 0.0f; }

#pragma unroll
    for (int c4 = 0; c4 < 4; ++c4) {
        float4 x[4];
#pragma unroll
        for (int q = 0; q < 4; ++q) x[q] = nr[c4 * 4 + q];
#pragma unroll
        for (int q = 0; q < 4; ++q) {
            const float* xp = (const float*)&x[q];
#pragma unroll
            for (int cc = 0; cc < 4; ++cc) {
                int k = (c4 * 4 + q) * 4 + cc;
                FMA20(as, xp[cc], &Wss[k * MSG]);
                FMA20(ad, xp[cc], &Wds[k * MSG]);
            }
        }
    }

    store_row_h(Ps + (size_t)n * RSTRIDE, as);
    store_row_h(Pd + (size_t)n * RSTRIDE, ad);
}

// Per edge: row = edge_attr[e] @ W[128:192] + b + Ps[src], written fp16 to CSR slot
// p = atomicAdd(cur[dst]) as one fully-dirty aligned 64B line.
__global__ __launch_bounds__(256) void pe_perm_kernel(const int* __restrict__ ei,
                                                      const float* __restrict__ edge_attr,
                                                      const float* __restrict__ W, const float* __restrict__ b,
                                                      const __half* __restrict__ Ps,
                                                      int* __restrict__ cur,
                                                      __half* __restrict__ PeP) {
    __shared__ float Ws[DF * MSG];
    __shared__ float bs[MSG];
    for (int i = threadIdx.x; i < DF * MSG; i += 256) Ws[i] = W[2 * DF * MSG + i];
    if (threadIdx.x < MSG) bs[threadIdx.x] = b[threadIdx.x];
    __syncthreads();

    int e = blockIdx.x * 256 + threadIdx.x;
    if (e >= EDGES) return;

    int src = ei[e];
    int dst = ei[EDGES + e];
    int p = atomicAdd(&cur[dst], 1);          // issue early; result needed only at the end

    // issue the Ps gather early too (3 loads from 3.2MB L2-resident table)
    const uint4* pr = (const uint4*)(Ps + (size_t)src * RSTRIDE);
    uint4 g0 = pr[0], g1 = pr[1];
    uint2 g2 = *(const uint2*)(pr + 2);

    const float4* er = (const float4*)(edge_attr + (size_t)e * DF);

    float acc[MSG];
#pragma unroll
    for (int j = 0; j < MSG; ++j) acc[j] = bs[j];

#pragma unroll
    for (int c4 = 0; c4 < 4; ++c4) {
        float4 x[4];
#pragma unroll
        for (int q = 0; q < 4; ++q) x[q] = er[c4 * 4 + q];
#pragma unroll
        for (int q = 0; q < 4; ++q) {
            const float* xp = (const float*)&x[q];
#pragma unroll
            for (int cc = 0; cc < 4; ++cc)
                FMA20(acc, xp[cc], &Ws[((c4 * 4 + q) * 4 + cc) * MSG]);
        }
    }

    // add Ps[src]
    {
        union { uint4 q; __half2 h2[4]; } a0, a1;
        union { uint2 q; __half2 h2[2]; } a2;
        a0.q = g0; a1.q = g1; a2.q = g2;
#pragma unroll
        for (int i = 0; i < 4; ++i) {
            float2 f = __half22float2(a0.h2[i]);
            acc[2 * i] += f.x; acc[2 * i + 1] += f.y;
        }
#pragma unroll
        for (int i = 0; i < 4; ++i) {
            float2 f = __half22float2(a1.h2[i]);
            acc[8 + 2 * i] += f.x; acc[9 + 2 * i] += f.y;
        }
#pragma unroll
        for (int i = 0; i < 2; ++i) {
            float2 f = __half22float2(a2.h2[i]);
            acc[16 + 2 * i] += f.x; acc[17 + 2 * i] += f.y;
        }
    }

    store_row_h(PeP + (size_t)p * RSTRIDE, acc);
}

// Node-centric aggregate: 4 lanes per node stream contiguous fp16 CSR rows,
// acc += relu(row + Pd[node]); quad shfl-reduce; 20->20->10 MLP; atomic into gacc.
__global__ __launch_bounds__(256) void agg_kernel(const int* __restrict__ rs,
                                                  const __half* __restrict__ PeP,
                                                  const __half* __restrict__ Pd,
                                                  const float* __restrict__ W1, const float* __restrict__ b1,
                                                  const float* __restrict__ W2, const float* __restrict__ b2,
                                                  const int* __restrict__ batch, float* __restrict__ gacc) {
    __shared__ float W1s[MSG * MSG], W2s[MSG * HID2], b1s[MSG], b2s[HID2];
    for (int i = threadIdx.x; i < MSG * MSG; i += 256) W1s[i] = W1[i];
    for (int i = threadIdx.x; i < MSG * HID2; i += 256) W2s[i] = W2[i];
    if (threadIdx.x < MSG) b1s[threadIdx.x] = b1[threadIdx.x];
    if (threadIdx.x < HID2) b2s[threadIdx.x] = b2[threadIdx.x];
    __syncthreads();

    int t = threadIdx.x;
    int node = blockIdx.x * 64 + (t >> 2);
    int lane = t & 3;

    float acc[MSG];
#pragma unroll
    for (int j = 0; j < MSG; ++j) acc[j] = 0.0f;

    if (node < NODES) {
        int s0 = rs[node];
        int deg = rs[node + 1] - s0;

        float pd[MSG];
        {
            const uint4* pr = (const uint4*)(Pd + (size_t)node * RSTRIDE);
            uint4 g0 = pr[0], g1 = pr[1];
            uint2 g2 = *(const uint2*)(pr + 2);
            union { uint4 q; __half2 h2[4]; } a0, a1;
            union { uint2 q; __half2 h2[2]; } a2;
            a0.q = g0; a1.q = g1; a2.q = g2;
#pragma unroll
            for (int i = 0; i < 4; ++i) {
                float2 f = __half22float2(a0.h2[i]);
                pd[2 * i] = f.x; pd[2 * i + 1] = f.y;
            }
#pragma unroll
            for (int i = 0; i < 4; ++i) {
                float2 f = __half22float2(a1.h2[i]);
                pd[8 + 2 * i] = f.x; pd[9 + 2 * i] = f.y;
            }
#pragma unroll
            for (int i = 0; i < 2; ++i) {
                float2 f = __half22float2(a2.h2[i]);
                pd[16 + 2 * i] = f.x; pd[17 + 2 * i] = f.y;
            }
        }

        for (int i = lane; i < deg; i += 4) {
            const uint4* rp = (const uint4*)(PeP + (size_t)(s0 + i) * RSTRIDE);
            uint4 q0 = rp[0], q1 = rp[1];
            uint2 q2 = *(const uint2*)(rp + 2);
            union { uint4 q; __half2 h2[4]; } a0, a1;
            union { uint2 q; __half2 h2[2]; } a2;
            a0.q = q0; a1.q = q1; a2.q = q2;
#pragma unroll
            for (int k = 0; k < 4; ++k) {
                float2 f = __half22float2(a0.h2[k]);
                acc[2 * k]     += fmaxf(f.x + pd[2 * k], 0.0f);
                acc[2 * k + 1] += fmaxf(f.y + pd[2 * k + 1], 0.0f);
            }
#pragma unroll
            for (int k = 0; k < 4; ++k) {
                float2 f = __half22float2(a1.h2[k]);
                acc[8 + 2 * k] += fmaxf(f.x + pd[8 + 2 * k], 0.0f);
                acc[9 + 2 * k] += fmaxf(f.y + pd[9 + 2 * k], 0.0f);
            }
#pragma unroll
            for (int k = 0; k < 2; ++k) {
                float2 f = __half22float2(a2.h2[k]);
                acc[16 + 2 * k] += fmaxf(f.x + pd[16 + 2 * k], 0.0f);
                acc[17 + 2 * k] += fmaxf(f.y + pd[17 + 2 * k], 0.0f);
            }
        }
    }

#pragma unroll
    for (int j = 0; j < MSG; ++j) acc[j] += __shfl_xor(acc[j], 1);
#pragma unroll
    for (int j = 0; j < MSG; ++j) acc[j] += __shfl_xor(acc[j], 2);

    if (node < NODES && lane == 0) {
        float t1[MSG];
#pragma unroll
        for (int j = 0; j < MSG; ++j) t1[j] = b1s[j];
#pragma unroll
        for (int k = 0; k < MSG; ++k)
#pragma unroll
            for (int j = 0; j < MSG; ++j) t1[j] = fmaf(acc[k], W1s[k * MSG + j], t1[j]);
#pragma unroll
        for (int j = 0; j < MSG; ++j) t1[j] = fmaxf(t1[j], 0.0f);

        float t2[HID2];
#pragma unroll
        for (int m = 0; m < HID2; ++m) t2[m] = b2s[m];
#pragma unroll
        for (int k = 0; k < MSG; ++k)
#pragma unroll
            for (int m = 0; m < HID2; ++m) t2[m] = fmaf(t1[k], W2s[k * HID2 + m], t2[m]);

        int g = batch[node];
        float* gr = gacc + (size_t)g * HID2;
#pragma unroll
        for (int m = 0; m < HID2; ++m) atomicAdd(gr + m, fmaxf(t2[m], 0.0f));
    }
}

__global__ void graph_kernel(const float* __restrict__ gacc,
                             const float* __restrict__ W3, const float* __restrict__ b3,
                             const float* __restrict__ W4, const float* __restrict__ b4,
                             float* __restrict__ out) {
    int g = blockIdx.x * blockDim.x + threadIdx.x;
    if (g >= GRAPHS) return;

    float h[HID2];
#pragma unroll
    for (int m = 0; m < HID2; ++m) h[m] = gacc[(size_t)g * HID2 + m];

    float t[HID2];
#pragma unroll
    for (int j = 0; j < HID2; ++j) {
        float s = b3[j];
#pragma unroll
        for (int k = 0; k < HID2; ++k) s = fmaf(h[k], W3[k * HID2 + j], s);
        t[j] = fmaxf(s, 0.0f);
    }
    float s = b4[0];
#pragma unroll
    for (int k = 0; k < HID2; ++k) s = fmaf(t[k], W4[k], s);
    out[g] = s;
}

extern "C" void kernel_launch(void* const* d_in, const int* in_sizes, int n_in,
                              void* d_out, int out_size, void* d_ws, size_t ws_size,
                              hipStream_t stream) {
    const int*   ei        = (const int*)  d_in[0];
    const float* node_attr = (const float*)d_in[1];
    const float* edge_attr = (const float*)d_in[2];
    const int*   batch     = (const int*)  d_in[3];
    const float* W_mpl     = (const float*)d_in[4];
    const float* b_mpl     = (const float*)d_in[5];
    const float* W1        = (const float*)d_in[6];
    const float* b1        = (const float*)d_in[7];
    const float* W2        = (const float*)d_in[8];
    const float* b2        = (const float*)d_in[9];
    const float* W3        = (const float*)d_in[10];
    const float* b3        = (const float*)d_in[11];
    const float* W4        = (const float*)d_in[12];
    const float* b4        = (const float*)d_in[13];
    float* out = (float*)d_out;

    // workspace layout (all offsets multiples of 64B)
    __half* PeP = (__half*)d_ws;                          // E*32 halves (51.2 MB), CSR-ordered, 64B rows
    __half* Ps  = PeP + (size_t)EDGES * RSTRIDE;          // N*32 halves (3.2 MB)
    __half* Pd  = Ps + (size_t)NODES * RSTRIDE;           // N*32 halves (3.2 MB)
    float* gacc = (float*)(Pd + (size_t)NODES * RSTRIDE); // G*10
    int* cnt    = (int*)(gacc + GRAPHS * HID2);           // N (padded 50176)
    int* rs     = cnt + 50176;                            // N+1 (padded)
    int* cur    = rs + 50176;                             // N (padded)
    int* bsum   = cur + 50176;                            // 256
    int* bscan  = bsum + 256;                             // 256

    int egrid = (EDGES + 255) / 256;   // 3125
    int ngrid = NB1;                   // 196

    hipLaunchKernelGGL(zero2_kernel, dim3(256), dim3(256), 0, stream, cnt, gacc);
    hipLaunchKernelGGL(count_kernel, dim3(egrid), dim3(256), 0, stream, ei, cnt);
    hipLaunchKernelGGL(scan_block, dim3(ngrid), dim3(256), 0, stream, cnt, rs, bsum, NODES);
    hipLaunchKernelGGL(scan_block, dim3(1), dim3(256), 0, stream, bsum, bscan, (int*)nullptr, NB1);
    hipLaunchKernelGGL(scan_fixup, dim3(ngrid), dim3(256), 0, stream, rs, cur, bscan);
    hipLaunchKernelGGL(pn_kernel, dim3(ngrid), dim3(256), 0, stream, node_attr, W_mpl, Ps, Pd);
    hipLaunchKernelGGL(pe_perm_kernel, dim3(egrid), dim3(256), 0, stream,
                       ei, edge_attr, W_mpl, b_mpl, Ps, cur, PeP);
    hipLaunchKernelGGL(agg_kernel, dim3((NODES + 63) / 64), dim3(256), 0, stream,
                       rs, PeP, Pd, W1, b1, W2, b2, batch, gacc);
    hipLaunchKernelGGL(graph_kernel, dim3(2), dim3(256), 0, stream, gacc, W3, b3, W4, b4, out);
}